// Round 10
// baseline (116.835 us; speedup 1.0000x reference)
//
#include <hip/hip_runtime.h>
#include <hip/hip_bf16.h>

typedef unsigned short u16;
typedef unsigned short ushort8v __attribute__((ext_vector_type(8)));
typedef __bf16 bf16x8 __attribute__((ext_vector_type(8)));
typedef float f32x4 __attribute__((ext_vector_type(4)));

#define NB 16   // batch
#define NK 32   // K slices
#define ND 256  // D
#define NL 256  // L1 == L2

__device__ __forceinline__ u16 f2bf(float f) {
    __hip_bfloat16 h = __float2bfloat16(f);
    return __builtin_bit_cast(u16, h);
}

__device__ __forceinline__ bf16x8 pack8(float4 a, float4 b) {
    ushort8v u;
    u[0] = f2bf(a.x); u[1] = f2bf(a.y); u[2] = f2bf(a.z); u[3] = f2bf(a.w);
    u[4] = f2bf(b.x); u[5] = f2bf(b.y); u[6] = f2bf(b.z); u[7] = f2bf(b.w);
    return __builtin_bit_cast(bf16x8, u);
}

// async global->LDS, 16B per lane; lds dst = wave-uniform base + lane*16
__device__ __forceinline__ void gload_lds16(const void* g, void* l) {
    __builtin_amdgcn_global_load_lds(
        (const __attribute__((address_space(1))) unsigned int*)g,
        (__attribute__((address_space(3))) unsigned int*)l, 16, 0, 0);
}

// Fragment-order layout for a 256x256 matrix X[r][c] (c = contraction dim):
//   buf[((rt*8 + ct)*64 + lane)*8 + (c&7)], rt=r>>4, ct=c>>5,
//   lane = (r&15) | (((c>>3)&3)<<4)
// => a wave's 16x16x32 MFMA fragment is 1 KiB contiguous; coalesced dwordx4 loads.

// ---------------- fused prep ----------------
__global__ void prep_kernel(const float* __restrict__ x1, const float* __restrict__ x2,
                            const float* __restrict__ W, const float* __restrict__ V,
                            const float* __restrict__ bb,
                            u16* __restrict__ x1f, u16* __restrict__ x2f, u16* __restrict__ Wf,
                            float* __restrict__ lin1, float* __restrict__ lin2) {
    int bid = blockIdx.x;
    int tid = threadIdx.x;
    if (bid < 4096) {
        const float* src; u16* dst; long f4;
        if (bid < 1024)      { src = x1; dst = x1f; f4 = (long)bid * 256 + tid; }
        else if (bid < 2048) { src = x2; dst = x2f; f4 = (long)(bid - 1024) * 256 + tid; }
        else                 { src = W;  dst = Wf;  f4 = (long)(bid - 2048) * 256 + tid; }
        long idx = f4 << 2;
        int mat = (int)(idx >> 16);
        int r = (int)((idx >> 8) & 255);
        int c = (int)(idx & 255);
        float4 v = ((const float4*)src)[f4];
        ushort4 o;
        o.x = f2bf(v.x); o.y = f2bf(v.y); o.z = f2bf(v.z); o.w = f2bf(v.w);
        int rt = r >> 4, ct = c >> 5;
        int lane = (r & 15) | (((c >> 3) & 3) << 4);
        long off = ((long)mat << 16) + (((rt << 3) + ct) << 9) + (lane << 3) + (c & 7);
        *(ushort4*)(dst + off) = o;
        return;
    }
    // ---- lin blocks (32): bid2 = (b, pass)
    int bid2 = bid - 4096;
    int b = bid2 >> 1, pass = bid2 & 1;
    int lane = tid & 63;
    int wv   = tid >> 6;
    int lrow = lane & 15;
    int lk8  = (lane >> 4) << 3;
    int j4   = (lane >> 4) << 2;
    int lbase = wv << 6;

    const f32x4 fz = {0.f, 0.f, 0.f, 0.f};
    const float* xp = (pass ? x2 : x1) + ((long)b << 16);
    const float* vp = V + (pass ? ND : 0);
    f32x4 acc[4][2];
#pragma unroll
    for (int i = 0; i < 4; ++i) { acc[i][0] = fz; acc[i][1] = fz; }
#pragma unroll
    for (int dt = 0; dt < 8; ++dt) {
        int d = (dt << 5) + lk8;
        bf16x8 af[4], bf[2];
#pragma unroll
        for (int lt = 0; lt < 4; ++lt) {
            const float4* s = (const float4*)(xp + ((long)((lbase + (lt << 4) + lrow)) << 8) + d);
            af[lt] = pack8(s[0], s[1]);
        }
#pragma unroll
        for (int nt = 0; nt < 2; ++nt) {
            const float4* s = (const float4*)(vp + (long)((nt << 4) + lrow) * (2 * ND) + d);
            bf[nt] = pack8(s[0], s[1]);
        }
#pragma unroll
        for (int nt = 0; nt < 2; ++nt)
#pragma unroll
            for (int lt = 0; lt < 4; ++lt)
                acc[lt][nt] = __builtin_amdgcn_mfma_f32_16x16x32_bf16(af[lt], bf[nt], acc[lt][nt], 0, 0, 0);
    }
    float* dst = (pass ? lin2 : lin1) + ((long)b << 13);
#pragma unroll
    for (int nt = 0; nt < 2; ++nt) {
        int kk = (nt << 4) + lrow;
        float add = pass ? 0.f : bb[kk];
#pragma unroll
        for (int lt = 0; lt < 4; ++lt) {
            float4 v;
            v.x = acc[lt][nt][0] + add; v.y = acc[lt][nt][1] + add;
            v.z = acc[lt][nt][2] + add; v.w = acc[lt][nt][3] + add;
            *(float4*)(dst + ((long)kk << 8) + lbase + (lt << 4) + j4) = v;
        }
    }
}

// ---------------- main fused kernel (R9 structure, UNCHANGED — diagnostic round) ----
__launch_bounds__(512, 6)
__global__ void ntn_main(const u16* __restrict__ x1f, const u16* __restrict__ x2f,
                         const u16* __restrict__ Wf,
                         const float* __restrict__ lin1, const float* __restrict__ lin2,
                         float* __restrict__ out) {
    __shared__ __align__(16) char ldsRaw[32768];   // x2 stage -> U^T -> epilogue chunks

    // supertile decode: 128-block supertiles of 8k x 4b x 4mq per XCD slot
    int bid = blockIdx.x;
    int xcd   = bid & 7;
    int j     = bid >> 3;
    int slot  = j >> 7;
    int inner = j & 127;
    int st    = (slot << 3) | xcd;     // 0..15
    int kg = st >> 2, bg = st & 3;
    int k  = (kg << 3) | (inner >> 4);
    int b  = (bg << 2) | ((inner >> 2) & 3);
    int mq = inner & 3;

    int tid  = threadIdx.x;
    int lane = tid & 63;
    int wid  = tid >> 6;
    int lrow = lane & 15;
    int j4   = (lane >> 4) << 2;

    // ---- async stage x2 m-quarter: 32 chunks of 1 KiB (frag-order is linear)
    {
        const char* src = (const char*)(x2f + ((long)b << 16) + ((long)mq << 14));
#pragma unroll
        for (int it = 0; it < 4; ++it) {
            int chunk = (it << 3) + wid;
            gload_lds16(src + (chunk << 10) + (lane << 4), ldsRaw + (chunk << 10));
        }
    }

    f32x4 acc[4][2];
    const f32x4 fz = {0.f, 0.f, 0.f, 0.f};
#pragma unroll
    for (int i = 0; i < 4; ++i) { acc[i][0] = fz; acc[i][1] = fz; }

    __syncthreads();   // x2 staged

    // ================= phase A: U^T[m'][d] =================
    {
        int wrA = wid >> 1;   // d-dim 0..3 (4 d-tiles each)
        int wcA = wid & 1;    // m-dim 0..1 (2 m-tiles each)
        const u16* wp = Wf + ((long)k << 16);
#pragma unroll
        for (int et = 0; et < 8; ++et) {
            bf16x8 af[4], bfr[2];
#pragma unroll
            for (int lt = 0; lt < 4; ++lt)
                af[lt] = *(const bf16x8*)(wp + (((((wrA << 2) + lt) << 3) + et) << 9) + (lane << 3));
#pragma unroll
            for (int nt = 0; nt < 2; ++nt)
                bfr[nt] = *(const bf16x8*)(ldsRaw + ((((((wcA << 1) + nt) << 3) + et) << 10) + (lane << 4)));
#pragma unroll
            for (int nt = 0; nt < 2; ++nt)
#pragma unroll
                for (int lt = 0; lt < 4; ++lt)
                    acc[lt][nt] = __builtin_amdgcn_mfma_f32_16x16x32_bf16(af[lt], bfr[nt], acc[lt][nt], 0, 0, 0);
        }
    }
    __syncthreads();   // all x2 LDS reads done; safe to overwrite with U^T

    // ---- write U^T[m' 64][d 256] u16 LDS (rows 512 B), swizzle byte^=((m&7)<<4)
    {
        int wrA = wid >> 1;
        int wcA = wid & 1;
#pragma unroll
        for (int lt = 0; lt < 4; ++lt) {
            int d0 = (wrA << 6) + (lt << 4) + j4;
#pragma unroll
            for (int nt = 0; nt < 2; ++nt) {
                int m = (wcA << 5) + (nt << 4) + lrow;   // 0..63
                ushort4 pk;
                pk.x = f2bf(acc[lt][nt][0]);
                pk.y = f2bf(acc[lt][nt][1]);
                pk.z = f2bf(acc[lt][nt][2]);
                pk.w = f2bf(acc[lt][nt][3]);
                *(ushort4*)(ldsRaw + (m << 9) + ((d0 << 1) ^ ((m & 7) << 4))) = pk;
            }
        }
    }
    __syncthreads();

#pragma unroll
    for (int i = 0; i < 4; ++i) { acc[i][0] = fz; acc[i][1] = fz; }

    // ================= phase B: D[m 64][l 256]; wave wid owns l-tiles 2*wid,2*wid+1 ====
    {
        const u16* x1p = x1f + ((long)b << 16);
        int lk8 = (lane >> 4) << 3;
#pragma unroll
        for (int dt = 0; dt < 8; ++dt) {
            int d = (dt << 5) + lk8;
            bf16x8 am[4], xl[2];
#pragma unroll
            for (int mt = 0; mt < 4; ++mt) {
                int m = (mt << 4) + lrow;
                am[mt] = *(const bf16x8*)(ldsRaw + (m << 9) + ((d << 1) ^ ((m & 7) << 4)));
            }
#pragma unroll
            for (int lt = 0; lt < 2; ++lt)
                xl[lt] = *(const bf16x8*)(x1p + (((((wid << 1) + lt) << 3) + dt) << 9) + (lane << 3));
#pragma unroll
            for (int lt = 0; lt < 2; ++lt)
#pragma unroll
                for (int mt = 0; mt < 4; ++mt)
                    acc[mt][lt] = __builtin_amdgcn_mfma_f32_16x16x32_bf16(am[mt], xl[lt], acc[mt][lt], 0, 0, 0);
        }
    }
    __syncthreads();   // all U^T reads done; safe to overwrite as f32 chunk

    // ================= epilogue: +lin1+lin2, relu, LDS transpose, coalesced stores ====
    {
        const float* l1p = lin1 + (((long)(b * NK + k)) << 8);
        const float* l2p = lin2 + (((long)(b * NK + k)) << 8) + (mq << 6);
        float* outp = out + (((long)(b * NK + k)) << 16) + (mq << 6);

#pragma unroll
        for (int c = 0; c < 2; ++c) {
            if ((wid >> 2) == c) {
                float rb[2];
#pragma unroll
                for (int lt = 0; lt < 2; ++lt)
                    rb[lt] = l1p[(wid << 5) + (lt << 4) + lrow];
#pragma unroll
                for (int mt = 0; mt < 4; ++mt) {
                    int mcol = (mt << 4) + j4;
                    float4 l2v = *(const float4*)(l2p + mcol);
#pragma unroll
                    for (int lt = 0; lt < 2; ++lt) {
                        int row = ((wid & 3) << 5) + (lt << 4) + lrow;   // chunk-local l 0..127
                        f32x4 v;
                        v[0] = acc[mt][lt][0] + rb[lt] + l2v.x;
                        v[1] = acc[mt][lt][1] + rb[lt] + l2v.y;
                        v[2] = acc[mt][lt][2] + rb[lt] + l2v.z;
                        v[3] = acc[mt][lt][3] + rb[lt] + l2v.w;
                        v[0] = v[0] > 0.f ? v[0] : 0.f;
                        v[1] = v[1] > 0.f ? v[1] : 0.f;
                        v[2] = v[2] > 0.f ? v[2] : 0.f;
                        v[3] = v[3] > 0.f ? v[3] : 0.f;
                        *(f32x4*)(ldsRaw + (row << 8) + ((mcol << 2) ^ ((row & 7) << 4))) = v;
                    }
                }
            }
            __syncthreads();
            // stream chunk: 32 KiB = 512 threads x f32x4 x 4 iters; 256 B runs per row
#pragma unroll
            for (int it = 0; it < 4; ++it) {
                int g = (it << 9) + tid;
                int row = g >> 4;       // 0..127
                int c4  = g & 15;       // 16B block within 256B row
                f32x4 v = *(const f32x4*)(ldsRaw + (row << 8) + ((c4 << 4) ^ ((row & 7) << 4)));
                __builtin_nontemporal_store(v, (f32x4*)(outp + ((long)((c << 7) + row) << 8) + (c4 << 2)));
            }
            if (c == 0) __syncthreads();
        }
    }
}

extern "C" void kernel_launch(void* const* d_in, const int* in_sizes, int n_in,
                              void* d_out, int out_size, void* d_ws, size_t ws_size,
                              hipStream_t stream) {
    const float* x1 = (const float*)d_in[0];
    const float* x2 = (const float*)d_in[1];
    const float* W  = (const float*)d_in[2];
    const float* V  = (const float*)d_in[3];
    const float* bb = (const float*)d_in[4];
    float* out = (float*)d_out;

    char* ws = (char*)d_ws;
    u16*   x1f  = (u16*)(ws);                               // 2 MiB
    u16*   x2f  = (u16*)(ws + (2l << 20));                  // 2 MiB
    u16*   Wf   = (u16*)(ws + (4l << 20));                  // 4 MiB
    float* lin1 = (float*)(ws + (8l << 20));                // 512 KiB
    float* lin2 = (float*)(ws + (8l << 20) + (512l << 10)); // 512 KiB

    hipLaunchKernelGGL(prep_kernel, dim3(4128), dim3(256), 0, stream,
                       x1, x2, W, V, bb, x1f, x2f, Wf, lin1, lin2);
    // DIAGNOSTIC: launch main twice (idempotent, identical output).
    // Instance 1 = cold-L2, instance 2 = warm-L2. Comparing dur/FETCH of the two
    // isolates input-fetch sensitivity; absolute counters (MfmaUtil, WRITE_SIZE,
    // Occupancy, VGPR) diagnose the ~2x gap vs the memory/MFMA floor.
    hipLaunchKernelGGL(ntn_main, dim3(2048), dim3(512), 0, stream,
                       x1f, x2f, Wf, lin1, lin2, out);
    hipLaunchKernelGGL(ntn_main, dim3(2048), dim3(512), 0, stream,
                       x1f, x2f, Wf, lin1, lin2, out);
}

// Round 11
// 76.251 us; speedup vs baseline: 1.5322x; 1.5322x over previous
//
#include <hip/hip_runtime.h>
#include <hip/hip_bf16.h>

typedef unsigned short u16;
typedef unsigned short ushort8v __attribute__((ext_vector_type(8)));
typedef __bf16 bf16x8 __attribute__((ext_vector_type(8)));
typedef float f32x4 __attribute__((ext_vector_type(4)));

#define NB 16   // batch
#define NK 32   // K slices
#define ND 256  // D
#define NL 256  // L1 == L2

__device__ __forceinline__ u16 f2bf(float f) {
    __hip_bfloat16 h = __float2bfloat16(f);
    return __builtin_bit_cast(u16, h);
}

__device__ __forceinline__ bf16x8 pack8(float4 a, float4 b) {
    ushort8v u;
    u[0] = f2bf(a.x); u[1] = f2bf(a.y); u[2] = f2bf(a.z); u[3] = f2bf(a.w);
    u[4] = f2bf(b.x); u[5] = f2bf(b.y); u[6] = f2bf(b.z); u[7] = f2bf(b.w);
    return __builtin_bit_cast(bf16x8, u);
}

// async global->LDS, 16B per lane; lds dst = wave-uniform base + lane*16
__device__ __forceinline__ void gload_lds16(const void* g, void* l) {
    __builtin_amdgcn_global_load_lds(
        (const __attribute__((address_space(1))) unsigned int*)g,
        (__attribute__((address_space(3))) unsigned int*)l, 16, 0, 0);
}

// lgkm-only barrier: does NOT drain vmcnt -> nontemporal stores stay in flight
__device__ __forceinline__ void barrier_lgkm() {
    asm volatile("s_waitcnt lgkmcnt(0)" ::: "memory");
    __builtin_amdgcn_s_barrier();
    asm volatile("" ::: "memory");
}

// Fragment-order layout for a 256x256 matrix X[r][c] (c = contraction dim):
//   buf[((rt*8 + ct)*64 + lane)*8 + (c&7)], rt=r>>4, ct=c>>5,
//   lane = (r&15) | (((c>>3)&3)<<4)
// => a wave's 16x16x32 MFMA fragment is 1 KiB contiguous; coalesced dwordx4 loads.

// ---------------- fused prep (unchanged) ----------------
__global__ void prep_kernel(const float* __restrict__ x1, const float* __restrict__ x2,
                            const float* __restrict__ W, const float* __restrict__ V,
                            const float* __restrict__ bb,
                            u16* __restrict__ x1f, u16* __restrict__ x2f, u16* __restrict__ Wf,
                            float* __restrict__ lin1, float* __restrict__ lin2) {
    int bid = blockIdx.x;
    int tid = threadIdx.x;
    if (bid < 4096) {
        const float* src; u16* dst; long f4;
        if (bid < 1024)      { src = x1; dst = x1f; f4 = (long)bid * 256 + tid; }
        else if (bid < 2048) { src = x2; dst = x2f; f4 = (long)(bid - 1024) * 256 + tid; }
        else                 { src = W;  dst = Wf;  f4 = (long)(bid - 2048) * 256 + tid; }
        long idx = f4 << 2;
        int mat = (int)(idx >> 16);
        int r = (int)((idx >> 8) & 255);
        int c = (int)(idx & 255);
        float4 v = ((const float4*)src)[f4];
        ushort4 o;
        o.x = f2bf(v.x); o.y = f2bf(v.y); o.z = f2bf(v.z); o.w = f2bf(v.w);
        int rt = r >> 4, ct = c >> 5;
        int lane = (r & 15) | (((c >> 3) & 3) << 4);
        long off = ((long)mat << 16) + (((rt << 3) + ct) << 9) + (lane << 3) + (c & 7);
        *(ushort4*)(dst + off) = o;
        return;
    }
    // ---- lin blocks (32): bid2 = (b, pass)
    int bid2 = bid - 4096;
    int b = bid2 >> 1, pass = bid2 & 1;
    int lane = tid & 63;
    int wv   = tid >> 6;
    int lrow = lane & 15;
    int lk8  = (lane >> 4) << 3;
    int j4   = (lane >> 4) << 2;
    int lbase = wv << 6;

    const f32x4 fz = {0.f, 0.f, 0.f, 0.f};
    const float* xp = (pass ? x2 : x1) + ((long)b << 16);
    const float* vp = V + (pass ? ND : 0);
    f32x4 acc[4][2];
#pragma unroll
    for (int i = 0; i < 4; ++i) { acc[i][0] = fz; acc[i][1] = fz; }
#pragma unroll
    for (int dt = 0; dt < 8; ++dt) {
        int d = (dt << 5) + lk8;
        bf16x8 af[4], bf[2];
#pragma unroll
        for (int lt = 0; lt < 4; ++lt) {
            const float4* s = (const float4*)(xp + ((long)((lbase + (lt << 4) + lrow)) << 8) + d);
            af[lt] = pack8(s[0], s[1]);
        }
#pragma unroll
        for (int nt = 0; nt < 2; ++nt) {
            const float4* s = (const float4*)(vp + (long)((nt << 4) + lrow) * (2 * ND) + d);
            bf[nt] = pack8(s[0], s[1]);
        }
#pragma unroll
        for (int nt = 0; nt < 2; ++nt)
#pragma unroll
            for (int lt = 0; lt < 4; ++lt)
                acc[lt][nt] = __builtin_amdgcn_mfma_f32_16x16x32_bf16(af[lt], bf[nt], acc[lt][nt], 0, 0, 0);
    }
    float* dst = (pass ? lin2 : lin1) + ((long)b << 13);
#pragma unroll
    for (int nt = 0; nt < 2; ++nt) {
        int kk = (nt << 4) + lrow;
        float add = pass ? 0.f : bb[kk];
#pragma unroll
        for (int lt = 0; lt < 4; ++lt) {
            float4 v;
            v.x = acc[lt][nt][0] + add; v.y = acc[lt][nt][1] + add;
            v.z = acc[lt][nt][2] + add; v.w = acc[lt][nt][3] + add;
            *(float4*)(dst + ((long)kk << 8) + lbase + (lt << 4) + j4) = v;
        }
    }
}

// ---------------- main fused kernel ----------------
// grid: 2048 supertiled blocks (k,b,mq 0..3); 512 threads = 8 waves; 48 KiB LDS
//       (3 blocks/CU). Phase B is software-pipelined in 4 l-quarters:
//       xl loads -> stream prev quarter's tile (NT stores NEWEST in vmcnt) ->
//       MFMA (vmcnt waits never drain stores) -> lgkm-barrier -> write tile ->
//       lgkm-barrier. Stores stay in flight across the whole loop.
__launch_bounds__(512, 6)
__global__ void ntn_main(const u16* __restrict__ x1f, const u16* __restrict__ x2f,
                         const u16* __restrict__ Wf,
                         const float* __restrict__ lin1, const float* __restrict__ lin2,
                         float* __restrict__ out) {
    __shared__ __align__(16) char ldsU[32768];   // x2 stage -> U^T[m 64][d 256] swizzled
    __shared__ __align__(16) char ldsE[16384];   // epilogue tile f32[64 l][64 m] swizzled

    // supertile decode: 128-block supertiles of 8k x 4b x 4mq per XCD slot
    int bid = blockIdx.x;
    int xcd   = bid & 7;
    int j     = bid >> 3;
    int slot  = j >> 7;
    int inner = j & 127;
    int st    = (slot << 3) | xcd;     // 0..15
    int kg = st >> 2, bg = st & 3;
    int k  = (kg << 3) | (inner >> 4);
    int b  = (bg << 2) | ((inner >> 2) & 3);
    int mq = inner & 3;

    int tid  = threadIdx.x;
    int lane = tid & 63;
    int wid  = tid >> 6;
    int lrow = lane & 15;
    int lk8  = (lane >> 4) << 3;
    int j4   = (lane >> 4) << 2;

    // ---- async stage x2 m-quarter: 32 chunks of 1 KiB (frag-order is linear)
    {
        const char* src = (const char*)(x2f + ((long)b << 16) + ((long)mq << 14));
#pragma unroll
        for (int it = 0; it < 4; ++it) {
            int chunk = (it << 3) + wid;
            gload_lds16(src + (chunk << 10) + (lane << 4), ldsU + (chunk << 10));
        }
    }

    const f32x4 fz = {0.f, 0.f, 0.f, 0.f};
    f32x4 accA[4][2];
#pragma unroll
    for (int i = 0; i < 4; ++i) { accA[i][0] = fz; accA[i][1] = fz; }

    __syncthreads();   // x2 staged (drains gload_lds)

    // ================= phase A: U^T[m' 64][d 256] =================
    {
        int wrA = wid >> 1;   // d-dim 0..3
        int wcA = wid & 1;    // m-dim 0..1
        const u16* wp = Wf + ((long)k << 16);
#pragma unroll
        for (int et = 0; et < 8; ++et) {
            bf16x8 af[4], bfr[2];
#pragma unroll
            for (int lt = 0; lt < 4; ++lt)
                af[lt] = *(const bf16x8*)(wp + (((((wrA << 2) + lt) << 3) + et) << 9) + (lane << 3));
#pragma unroll
            for (int nt = 0; nt < 2; ++nt)
                bfr[nt] = *(const bf16x8*)(ldsU + ((((((wcA << 1) + nt) << 3) + et) << 10) + (lane << 4)));
#pragma unroll
            for (int nt = 0; nt < 2; ++nt)
#pragma unroll
                for (int lt = 0; lt < 4; ++lt)
                    accA[lt][nt] = __builtin_amdgcn_mfma_f32_16x16x32_bf16(af[lt], bfr[nt], accA[lt][nt], 0, 0, 0);
        }
    }
    __syncthreads();   // all x2 LDS reads done; safe to overwrite with U^T

    // ---- write U^T[m 64][d 256] u16 (rows 512 B), swizzle byte^=((m&7)<<4)
    {
        int wrA = wid >> 1;
        int wcA = wid & 1;
#pragma unroll
        for (int lt = 0; lt < 4; ++lt) {
            int d0 = (wrA << 6) + (lt << 4) + j4;
#pragma unroll
            for (int nt = 0; nt < 2; ++nt) {
                int m = (wcA << 5) + (nt << 4) + lrow;   // 0..63
                ushort4 pk;
                pk.x = f2bf(accA[lt][nt][0]);
                pk.y = f2bf(accA[lt][nt][1]);
                pk.z = f2bf(accA[lt][nt][2]);
                pk.w = f2bf(accA[lt][nt][3]);
                *(ushort4*)(ldsU + (m << 9) + ((d0 << 1) ^ ((m & 7) << 4))) = pk;
            }
        }
    }
    __syncthreads();   // U^T visible

    // ================= phase B: 4 l-quarters, pipelined with stores =================
    // wave role: l-tile ltq = wid&3 (within quarter), m-pair mp = wid>>2 (m-tiles 2mp,2mp+1)
    {
        const u16* x1p = x1f + ((long)b << 16);
        int ltq = wid & 3;
        int mp  = wid >> 2;
        const float* l1p = lin1 + (((long)(b * NK + k)) << 8);
        const float* l2p = lin2 + (((long)(b * NK + k)) << 8) + (mq << 6);
        float* outp = out + (((long)(b * NK + k)) << 16) + (mq << 6);

        float4 l2v[2];
        l2v[0] = *(const float4*)(l2p + (mp << 5) + j4);
        l2v[1] = *(const float4*)(l2p + (mp << 5) + 16 + j4);

#pragma unroll
        for (int q = 0; q < 4; ++q) {
            // 1. issue this quarter's x1 frag loads FIRST (oldest in vmcnt)
            bf16x8 xl[8];
#pragma unroll
            for (int dt = 0; dt < 8; ++dt)
                xl[dt] = *(const bf16x8*)(x1p + ((((((q << 2) + ltq) << 3) + dt) << 9)) + (lane << 3));
            __builtin_amdgcn_sched_barrier(0);   // pin: xl loads before stream stores

            // 2. stream previous quarter's tile: LDS -> NT stores (newest in vmcnt)
            if (q > 0) {
#pragma unroll
                for (int it = 0; it < 2; ++it) {
                    int g = (it << 9) + tid;
                    int row = g >> 4;       // 0..63 chunk-local l
                    int c4  = g & 15;       // 16B block within 256B row
                    f32x4 v = *(const f32x4*)(ldsE + (row << 8) + ((c4 << 4) ^ ((row & 7) << 4)));
                    __builtin_nontemporal_store(v,
                        (f32x4*)(outp + ((long)(((q - 1) << 6) + row) << 8) + (c4 << 2)));
                }
            }

            // 3. MFMA: waiting for xl needs vmcnt(<=2 stores outstanding), no store drain
            f32x4 acc[2] = {fz, fz};
#pragma unroll
            for (int dt = 0; dt < 8; ++dt) {
                int d = (dt << 5) + lk8;
#pragma unroll
                for (int mt = 0; mt < 2; ++mt) {
                    int m = (mp << 5) + (mt << 4) + lrow;
                    bf16x8 am = *(const bf16x8*)(ldsU + (m << 9) + ((d << 1) ^ ((m & 7) << 4)));
                    acc[mt] = __builtin_amdgcn_mfma_f32_16x16x32_bf16(am, xl[dt], acc[mt], 0, 0, 0);
                }
            }

            // 4. all waves done streaming ldsE (their reads are lgkm) -> safe to overwrite
            barrier_lgkm();

            // 5. epilogue math + write tile: lane's l fixed; float4 along m
            {
                float rb = l1p[(q << 6) + (ltq << 4) + lrow];
                int row = (ltq << 4) + lrow;                 // chunk-local l 0..63
#pragma unroll
                for (int mt = 0; mt < 2; ++mt) {
                    int mloc = (mp << 5) + (mt << 4) + j4;
                    f32x4 v;
                    v[0] = acc[mt][0] + rb + l2v[mt].x;
                    v[1] = acc[mt][1] + rb + l2v[mt].y;
                    v[2] = acc[mt][2] + rb + l2v[mt].z;
                    v[3] = acc[mt][3] + rb + l2v[mt].w;
                    v[0] = v[0] > 0.f ? v[0] : 0.f;
                    v[1] = v[1] > 0.f ? v[1] : 0.f;
                    v[2] = v[2] > 0.f ? v[2] : 0.f;
                    v[3] = v[3] > 0.f ? v[3] : 0.f;
                    *(f32x4*)(ldsE + (row << 8) + ((mloc << 2) ^ ((row & 7) << 4))) = v;
                }
            }

            // 6. tile visible to all waves
            barrier_lgkm();
        }

        // final flush: stream quarter 3
#pragma unroll
        for (int it = 0; it < 2; ++it) {
            int g = (it << 9) + tid;
            int row = g >> 4;
            int c4  = g & 15;
            f32x4 v = *(const f32x4*)(ldsE + (row << 8) + ((c4 << 4) ^ ((row & 7) << 4)));
            __builtin_nontemporal_store(v,
                (f32x4*)(outp + ((long)((3 << 6) + row) << 8) + (c4 << 2)));
        }
    }
}

extern "C" void kernel_launch(void* const* d_in, const int* in_sizes, int n_in,
                              void* d_out, int out_size, void* d_ws, size_t ws_size,
                              hipStream_t stream) {
    const float* x1 = (const float*)d_in[0];
    const float* x2 = (const float*)d_in[1];
    const float* W  = (const float*)d_in[2];
    const float* V  = (const float*)d_in[3];
    const float* bb = (const float*)d_in[4];
    float* out = (float*)d_out;

    char* ws = (char*)d_ws;
    u16*   x1f  = (u16*)(ws);                               // 2 MiB
    u16*   x2f  = (u16*)(ws + (2l << 20));                  // 2 MiB
    u16*   Wf   = (u16*)(ws + (4l << 20));                  // 4 MiB
    float* lin1 = (float*)(ws + (8l << 20));                // 512 KiB
    float* lin2 = (float*)(ws + (8l << 20) + (512l << 10)); // 512 KiB

    hipLaunchKernelGGL(prep_kernel, dim3(4128), dim3(256), 0, stream,
                       x1, x2, W, V, bb, x1f, x2f, Wf, lin1, lin2);
    hipLaunchKernelGGL(ntn_main, dim3(2048), dim3(512), 0, stream,
                       x1f, x2f, Wf, lin1, lin2, out);
}